// Round 18
// baseline (148.867 us; speedup 1.0000x reference)
//
#include <hip/hip_runtime.h>

#define BT 16384
#define DK 4096
#define NE 64
#define BM 32                 // rows per block -> grid 512 = 2 blocks/CU
#define NSTG 128              // stages of 32 k (one k-group each)
#define NPROBS (BT * NE)
#define NIDX (NPROBS)
#define NWTS (NPROBS + BT * 2)

typedef __bf16 bf16x8 __attribute__((ext_vector_type(8)));
typedef float f32x4 __attribute__((ext_vector_type(4)));

__device__ __forceinline__ unsigned asu(float f) { return __builtin_bit_cast(unsigned, f); }
__device__ __forceinline__ float asf(unsigned u) { return __builtin_bit_cast(float, u); }

__device__ __forceinline__ void gl_lds16(const void* g, void* l) {
    __builtin_amdgcn_global_load_lds(
        (const __attribute__((address_space(1))) unsigned int*)g,
        (__attribute__((address_space(3))) unsigned int*)l, 16, 0, 0);
}

// Split 8 f32 into 3 bf16 planes (truncation split; residuals exact in f32).
__device__ __forceinline__ void split3(const float* xx, uint4* pl) {
    unsigned h0[8], h1[8], h2[8];
#pragma unroll
    for (int j = 0; j < 8; ++j) {
        const float xf = xx[j];
        const unsigned a0 = asu(xf) & 0xFFFF0000u;
        const float r1 = xf - asf(a0);
        const unsigned a1 = asu(r1) & 0xFFFF0000u;
        const float r2 = r1 - asf(a1);
        const unsigned a2 = asu(r2) & 0xFFFF0000u;
        h0[j] = a0; h1[j] = a1; h2[j] = a2;
    }
    pl[0] = make_uint4((h0[0] >> 16) | (h0[1] & 0xFFFF0000u), (h0[2] >> 16) | (h0[3] & 0xFFFF0000u),
                       (h0[4] >> 16) | (h0[5] & 0xFFFF0000u), (h0[6] >> 16) | (h0[7] & 0xFFFF0000u));
    pl[1] = make_uint4((h1[0] >> 16) | (h1[1] & 0xFFFF0000u), (h1[2] >> 16) | (h1[3] & 0xFFFF0000u),
                       (h1[4] >> 16) | (h1[5] & 0xFFFF0000u), (h1[6] >> 16) | (h1[7] & 0xFFFF0000u));
    pl[2] = make_uint4((h2[0] >> 16) | (h2[1] & 0xFFFF0000u), (h2[2] >> 16) | (h2[3] & 0xFFFF0000u),
                       (h2[4] >> 16) | (h2[5] & 0xFFFF0000u), (h2[6] >> 16) | (h2[7] & 0xFFFF0000u));
}

// prep: W (64 x 4096 f32) -> 3 bf16 planes in B-fragment order (validated R11+).
// WF idx = (ks*4 + et)*3*64 + p*64 + l : k = ks*32 + (l>>4)*8 + j, e = et*16 + (l&15)
__global__ __launch_bounds__(256) void w_prep(
    const float* __restrict__ W, uint4* __restrict__ WF)
{
    const int g  = blockIdx.x * 256 + threadIdx.x;
    const int e  = g >> 9;
    const int kg = g & 511;
    const float4 v0 = *(const float4*)(W + (long)e * DK + kg * 8);
    const float4 v1 = *(const float4*)(W + (long)e * DK + kg * 8 + 4);
    float xx[8] = {v0.x, v0.y, v0.z, v0.w, v1.x, v1.y, v1.z, v1.w};
    uint4 pl[3];
    split3(xx, pl);
    const int ks = kg >> 2;
    const int l  = (e & 15) | ((kg & 3) << 4);
    const int et = e >> 4;
#pragma unroll
    for (int p = 0; p < 3; ++p)
        WF[((ks * 4 + et) * 3 + p) * 64 + l] = pl[p];
}

// Main: 512 blocks x 32 rows (2 blocks/CU), 8 waves = et(4) x rh(2).
// Each wave: 16 rows x 16 experts, FULL K (no split-K, no combine).
// Single-barrier pipeline: stage s+1 (X 1KB + B 12KB block-wide) issued at
// the TOP of stage s into the spare buffers -> a full compute phase to land;
// one __syncthreads per stage is the only drain point. Inner loop is pure
// ds_read_b128 + split3 + 6 MFMA (no VMEM consumption -> no convoy).
__global__ __launch_bounds__(512) void token_router(
    const float* __restrict__ x, const uint4* __restrict__ WF,
    float* __restrict__ out)
{
    __shared__ float4 xs4[2 * 256];          // 8 KB: [buf][32 rows][8 quads] swizzled
    __shared__ uint4  bs[2 * 768];           // 24 KB: [buf][12 frag][64]
    __shared__ float  lg[BM * 68 + 2 * BM];  // 9 KB

    const int tid  = threadIdx.x;
    const int wv   = tid >> 6;
    const int lane = tid & 63;
    const int et   = wv & 3;          // expert tile (16 experts)
    const int rh   = wv >> 2;         // row half
    const long rowbase = (long)blockIdx.x * BM;

    // X staging (waves 0-3): inst covers rows wv*8..wv*8+7, lane l ->
    // row wv*8+(l>>3), slot sq=l&7 holds global quad sq^(l>>3) (pre-swizzled).
    const int xr3 = lane >> 3;               // row mod 8
    const int ssq = lane & 7;
    const float* gxs = x + (rowbase + (wv & 3) * 8 + xr3) * (long)DK
                         + ((ssq ^ xr3) << 2);
    // B staging: all waves stage frag-block wv; waves 0-3 also 8+wv.
    const uint4* gbs0 = WF + wv * 64 + lane;
    const uint4* gbs1 = WF + (8 + wv) * 64 + lane;

    // A-frag read coords: row rl, k-octet o2/2; swizzled slot = q ^ (rl&7)
    const int rl  = rh * 16 + (lane & 15);
    const int o2  = (lane >> 4) * 2;
    const int rsw = rl & 7;

    f32x4 acc = {0.f, 0.f, 0.f, 0.f};

    // prologue: stage 0 -> buf 0
    if (wv < 4) {
        gl_lds16(gxs, xs4 + wv * 64);
        gl_lds16(gbs1, bs + (8 + wv) * 64);
    }
    gl_lds16(gbs0, bs + wv * 64);
    __syncthreads();

    for (int s = 0; s < NSTG; ++s) {
        const int pb = (s & 1);
        const int nb = pb ^ 1;
        // (A) issue stage s+1 staging into spare buffers (drained at barrier)
        if (s + 1 < NSTG) {
            if (wv < 4) {
                gl_lds16(gxs + (s + 1) * 32, xs4 + nb * 256 + wv * 64);
                gl_lds16(gbs1 + (s + 1) * 768, bs + nb * 768 + (8 + wv) * 64);
            }
            gl_lds16(gbs0 + (s + 1) * 768, bs + nb * 768 + wv * 64);
        }
        // (B) compute stage s from LDS
        uint4 b[3];
#pragma unroll
        for (int p = 0; p < 3; ++p)
            b[p] = bs[pb * 768 + (et * 3 + p) * 64 + lane];
        const float4 alo = xs4[pb * 256 + rl * 8 + (o2 ^ rsw)];
        const float4 ahi = xs4[pb * 256 + rl * 8 + ((o2 + 1) ^ rsw)];
        float xx[8] = {alo.x, alo.y, alo.z, alo.w, ahi.x, ahi.y, ahi.z, ahi.w};
        uint4 pl[3];
        split3(xx, pl);
        const bf16x8 A0 = __builtin_bit_cast(bf16x8, pl[0]);
        const bf16x8 A1 = __builtin_bit_cast(bf16x8, pl[1]);
        const bf16x8 A2 = __builtin_bit_cast(bf16x8, pl[2]);
        const bf16x8 B0 = __builtin_bit_cast(bf16x8, b[0]);
        const bf16x8 B1 = __builtin_bit_cast(bf16x8, b[1]);
        const bf16x8 B2 = __builtin_bit_cast(bf16x8, b[2]);
        acc = __builtin_amdgcn_mfma_f32_16x16x32_bf16(A0, B0, acc, 0, 0, 0);
        acc = __builtin_amdgcn_mfma_f32_16x16x32_bf16(A0, B1, acc, 0, 0, 0);
        acc = __builtin_amdgcn_mfma_f32_16x16x32_bf16(A1, B0, acc, 0, 0, 0);
        acc = __builtin_amdgcn_mfma_f32_16x16x32_bf16(A1, B1, acc, 0, 0, 0);
        acc = __builtin_amdgcn_mfma_f32_16x16x32_bf16(A0, B2, acc, 0, 0, 0);
        acc = __builtin_amdgcn_mfma_f32_16x16x32_bf16(A2, B0, acc, 0, 0, 0);
        // (C) single drain point per stage
        __syncthreads();
    }

    // ---- logits (C/D: col = lane&15, row = (lane>>4)*4 + jj), single owner ----
#pragma unroll
    for (int jj = 0; jj < 4; ++jj) {
        const int row = rh * 16 + (lane >> 4) * 4 + jj;
        lg[row * 68 + et * 16 + (lane & 15)] = acc[jj];
    }
    __syncthreads();

    // ---- per-row softmax stats + stable top-2 (one thread per row) ----
    float* rowm   = lg + BM * 68;
    float* rowinv = rowm + BM;
    if (tid < BM) {
        const int row = tid;
        float m = -3.4e38f;
        for (int e = 0; e < NE; ++e) m = fmaxf(m, lg[row * 68 + e]);
        float s = 0.f;
        float v1 = -1.f, v2 = -1.f;
        int   i1 = 0,    i2 = 0;
        for (int e = 0; e < NE; ++e) {
            const float p = __expf(lg[row * 68 + e] - m);
            s += p;
            if (p > v1)      { v2 = v1; i2 = i1; v1 = p; i1 = e; }
            else if (p > v2) { v2 = p; i2 = e; }
        }
        const float inv = 1.f / s;
        rowm[row]   = m;
        rowinv[row] = inv;
        const long grow = rowbase + row;
        const float p1 = v1 * inv, p2 = v2 * inv;
        const float dn = p1 + p2 + 1e-9f;
        out[NIDX + grow * 2 + 0] = (float)i1;
        out[NIDX + grow * 2 + 1] = (float)i2;
        out[NWTS + grow * 2 + 0] = p1 / dn;
        out[NWTS + grow * 2 + 1] = p2 / dn;
    }
    __syncthreads();

    // ---- probs write: 512 threads x 1 float4, coalesced ----
    {
        const int row = tid >> 4;
        const int e0  = (tid & 15) << 2;
        const float m = rowm[row], inv = rowinv[row];
        const long grow = rowbase + row;
        const float4 l4 = *reinterpret_cast<const float4*>(&lg[row * 68 + e0]);
        float4 p;
        p.x = __expf(l4.x - m) * inv;
        p.y = __expf(l4.y - m) * inv;
        p.z = __expf(l4.z - m) * inv;
        p.w = __expf(l4.w - m) * inv;
        *reinterpret_cast<float4*>(&out[grow * (long)NE + e0]) = p;
    }
}

extern "C" void kernel_launch(void* const* d_in, const int* in_sizes, int n_in,
                              void* d_out, int out_size, void* d_ws, size_t ws_size,
                              hipStream_t stream) {
    const float* x = (const float*)d_in[0];
    const float* W = (const float*)d_in[1];
    float* out = (float*)d_out;
    uint4* WF  = (uint4*)d_ws;   // 1.5 MB fragment-ordered W planes

    w_prep<<<dim3(128), dim3(256), 0, stream>>>(W, WF);
    token_router<<<dim3(BT / BM), dim3(512), 0, stream>>>(x, WF, out);
}

// Round 19
// 91.210 us; speedup vs baseline: 1.6321x; 1.6321x over previous
//
#include <hip/hip_runtime.h>

#define BT 16384
#define DK 4096
#define NE 64
#define BM 32                 // rows per block -> grid 512 = 2 blocks/CU
#define NSTG 32               // stages of 32k per kh-slice (kh split-K 4)
#define NPROBS (BT * NE)
#define NIDX (NPROBS)
#define NWTS (NPROBS + BT * 2)

typedef __bf16 bf16x8 __attribute__((ext_vector_type(8)));
typedef float f32x16 __attribute__((ext_vector_type(16)));

__device__ __forceinline__ unsigned asu(float f) { return __builtin_bit_cast(unsigned, f); }
__device__ __forceinline__ float asf(unsigned u) { return __builtin_bit_cast(float, u); }

__device__ __forceinline__ void gl_lds16(const void* g, void* l) {
    __builtin_amdgcn_global_load_lds(
        (const __attribute__((address_space(1))) unsigned int*)g,
        (__attribute__((address_space(3))) unsigned int*)l, 16, 0, 0);
}

// Split 8 f32 into 3 bf16 planes (truncation split; residuals exact in f32).
__device__ __forceinline__ void split3(const float* xx, uint4* pl) {
    unsigned h0[8], h1[8], h2[8];
#pragma unroll
    for (int j = 0; j < 8; ++j) {
        const float xf = xx[j];
        const unsigned a0 = asu(xf) & 0xFFFF0000u;
        const float r1 = xf - asf(a0);
        const unsigned a1 = asu(r1) & 0xFFFF0000u;
        const float r2 = r1 - asf(a1);
        const unsigned a2 = asu(r2) & 0xFFFF0000u;
        h0[j] = a0; h1[j] = a1; h2[j] = a2;
    }
    pl[0] = make_uint4((h0[0] >> 16) | (h0[1] & 0xFFFF0000u), (h0[2] >> 16) | (h0[3] & 0xFFFF0000u),
                       (h0[4] >> 16) | (h0[5] & 0xFFFF0000u), (h0[6] >> 16) | (h0[7] & 0xFFFF0000u));
    pl[1] = make_uint4((h1[0] >> 16) | (h1[1] & 0xFFFF0000u), (h1[2] >> 16) | (h1[3] & 0xFFFF0000u),
                       (h1[4] >> 16) | (h1[5] & 0xFFFF0000u), (h1[6] >> 16) | (h1[7] & 0xFFFF0000u));
    pl[2] = make_uint4((h2[0] >> 16) | (h2[1] & 0xFFFF0000u), (h2[2] >> 16) | (h2[3] & 0xFFFF0000u),
                       (h2[4] >> 16) | (h2[5] & 0xFFFF0000u), (h2[6] >> 16) | (h2[7] & 0xFFFF0000u));
}

// prep: W -> 3 bf16 planes in 32x32x16 B-fragment order.
// WF idx = kst*384 + eh*192 + p*64 + l : expert = eh*32 + (l&31),
// k = kst*16 + (l>>5)*8 + j. (A uses the same (l>>5, j) k-map -> k-pairing
// is self-consistent regardless of HW's internal wiring; C/D map is the
// m74/m101-verified one.)
__global__ __launch_bounds__(256) void w_prep(
    const float* __restrict__ W, uint4* __restrict__ WF)
{
    const int g  = blockIdx.x * 256 + threadIdx.x;   // 32768 threads
    const int e  = g >> 9;
    const int kg = g & 511;                          // k-octet
    const float4 v0 = *(const float4*)(W + (long)e * DK + kg * 8);
    const float4 v1 = *(const float4*)(W + (long)e * DK + kg * 8 + 4);
    float xx[8] = {v0.x, v0.y, v0.z, v0.w, v1.x, v1.y, v1.z, v1.w};
    uint4 pl[3];
    split3(xx, pl);
    const int kst = kg >> 1;
    const int l   = (e & 31) | ((kg & 1) << 5);
    const int eh  = e >> 5;
#pragma unroll
    for (int p = 0; p < 3; ++p)
        WF[(long)kst * 384 + eh * 192 + p * 64 + l] = pl[p];
}

// Main: 512 blocks x 32 rows (2 blocks/CU), 8 waves = eh(2) x kh(4).
// Wave: 32 rows x 32 experts x 1024 k, acc = ONE f32x16.
// X: block-cooperative gload_lds staging (R17-verified swizzle), dbuf,
//    issued a full stage ahead; ONE barrier per stage.
// B: dense lane-linear VMEM from WF (L2-resident), register double-buffered,
//    issued one substep ahead. Never touches LDS.
__global__ __launch_bounds__(512) void token_router(
    const float* __restrict__ x, const uint4* __restrict__ WF,
    float* __restrict__ out)
{
    __shared__ float4 xs4[2 * 4 * 256];      // 32 KB: [buf][slice kh][32 rows][8 quads]
    __shared__ float  lg[BM * 68 + 2 * BM];  // 9 KB

    const int tid  = threadIdx.x;
    const int wv   = tid >> 6;
    const int lane = tid & 63;
    const int eh   = wv & 1;          // expert half (32 experts)
    const int kh   = wv >> 1;         // K quarter (1024 k)
    const long rowbase = (long)blockIdx.x * BM;

    // staging: wave does insts j=wv (slice wv>>2) and j=wv+8 (slice 2+(wv>>2)),
    // row-group wv&3. lane -> row grp*8+(l>>3), slot l&7 holds quad (l&7)^(l>>3).
    const int sr = lane >> 3, sq = lane & 7;
    const float* gxa = x + (rowbase + (wv & 3) * 8 + sr) * (long)DK
                         + (wv >> 2) * 1024 + ((sq ^ sr) << 2);
    const float* gxb = gxa + 2048;           // slice +2
    const int dsta = (wv >> 2) * 256 + (wv & 3) * 64 + lane;
    const int dstb = dsta + 512;

    // A-read coords: row r = lane&31 in slice kh; slot = Q ^ (r&7)
    const int rr  = lane & 31;
    const int rsw = rr & 7;
    const int xbase = kh * 256 + rr * 8;

    // B source: kst = kh*64 + s*2 + t
    const uint4* wfl = WF + eh * 192 + lane;

    f32x16 acc;
#pragma unroll
    for (int i = 0; i < 16; ++i) acc[i] = 0.f;

    uint4 bc0, bc1, bc2, bn0, bn1, bn2;

    // prologue: stage X(0) -> buf0; load B(kh*64) -> current set
    gl_lds16(gxa, xs4 + dsta);
    gl_lds16(gxb, xs4 + dstb);
    {
        const long k0 = (long)(kh * 64) * 384;
        bc0 = wfl[k0]; bc1 = wfl[k0 + 64]; bc2 = wfl[k0 + 128];
    }
    __syncthreads();

#define COMPUTE(PB, T, B0r, B1r, B2r) do {                                    \
    const int qb = (T) * 4 + (lane >> 5) * 2;                                 \
    const float4 alo = xs4[(PB) + xbase + (qb ^ rsw)];                        \
    const float4 ahi = xs4[(PB) + xbase + ((qb + 1) ^ rsw)];                  \
    float xx[8] = {alo.x, alo.y, alo.z, alo.w, ahi.x, ahi.y, ahi.z, ahi.w};   \
    uint4 pl[3];                                                              \
    split3(xx, pl);                                                           \
    const bf16x8 A0 = __builtin_bit_cast(bf16x8, pl[0]);                      \
    const bf16x8 A1 = __builtin_bit_cast(bf16x8, pl[1]);                      \
    const bf16x8 A2 = __builtin_bit_cast(bf16x8, pl[2]);                      \
    const bf16x8 B0 = __builtin_bit_cast(bf16x8, B0r);                        \
    const bf16x8 B1 = __builtin_bit_cast(bf16x8, B1r);                        \
    const bf16x8 B2 = __builtin_bit_cast(bf16x8, B2r);                        \
    acc = __builtin_amdgcn_mfma_f32_32x32x16_bf16(A0, B0, acc, 0, 0, 0);      \
    acc = __builtin_amdgcn_mfma_f32_32x32x16_bf16(A0, B1, acc, 0, 0, 0);      \
    acc = __builtin_amdgcn_mfma_f32_32x32x16_bf16(A1, B0, acc, 0, 0, 0);      \
    acc = __builtin_amdgcn_mfma_f32_32x32x16_bf16(A1, B1, acc, 0, 0, 0);      \
    acc = __builtin_amdgcn_mfma_f32_32x32x16_bf16(A0, B2, acc, 0, 0, 0);      \
    acc = __builtin_amdgcn_mfma_f32_32x32x16_bf16(A2, B0, acc, 0, 0, 0);      \
} while (0)

    for (int s = 0; s < NSTG; ++s) {
        const int pb = (s & 1) * 1024;
        const int nb = pb ^ 1024;
        if (s + 1 < NSTG) {                  // X(s+1): full stage to land
            gl_lds16(gxa + (s + 1) * 32, xs4 + nb + dsta);
            gl_lds16(gxb + (s + 1) * 32, xs4 + nb + dstb);
        }
        // substep 0: issue B(t=1), compute with current set
        {
            const long kn = ((long)(kh * 64 + s * 2 + 1)) * 384;
            bn0 = wfl[kn]; bn1 = wfl[kn + 64]; bn2 = wfl[kn + 128];
            COMPUTE(pb, 0, bc0, bc1, bc2);
        }
        // substep 1: issue B(next stage t=0), compute with spare set
        {
            if (s + 1 < NSTG) {
                const long kn = ((long)(kh * 64 + (s + 1) * 2)) * 384;
                bc0 = wfl[kn]; bc1 = wfl[kn + 64]; bc2 = wfl[kn + 128];
            }
            COMPUTE(pb, 1, bn0, bn1, bn2);
        }
        __syncthreads();                     // single drain point per stage
    }
#undef COMPUTE

    // ---- split-K combine: 4 barrier-phases over kh, fixed order ----
    // C/D map (m74/m101): col = lane&31, row = (reg&3) + 8*(reg>>2) + 4*(lane>>5)
#pragma unroll
    for (int ph = 0; ph < 4; ++ph) {
        if (kh == ph) {
            const int col = eh * 32 + (lane & 31);
            const int rbase = 4 * (lane >> 5);
#pragma unroll
            for (int rg = 0; rg < 16; ++rg) {
                const int row = (rg & 3) + 8 * (rg >> 2) + rbase;
                if (ph == 0) lg[row * 68 + col]  = acc[rg];
                else         lg[row * 68 + col] += acc[rg];
            }
        }
        __syncthreads();
    }

    // ---- per-row softmax stats + stable top-2 (one thread per row) ----
    float* rowm   = lg + BM * 68;
    float* rowinv = rowm + BM;
    if (tid < BM) {
        const int row = tid;
        float m = -3.4e38f;
        for (int e = 0; e < NE; ++e) m = fmaxf(m, lg[row * 68 + e]);
        float s = 0.f;
        float v1 = -1.f, v2 = -1.f;
        int   i1 = 0,    i2 = 0;
        for (int e = 0; e < NE; ++e) {
            const float p = __expf(lg[row * 68 + e] - m);
            s += p;
            if (p > v1)      { v2 = v1; i2 = i1; v1 = p; i1 = e; }
            else if (p > v2) { v2 = p; i2 = e; }
        }
        const float inv = 1.f / s;
        rowm[row]   = m;
        rowinv[row] = inv;
        const long grow = rowbase + row;
        const float p1 = v1 * inv, p2 = v2 * inv;
        const float dn = p1 + p2 + 1e-9f;
        out[NIDX + grow * 2 + 0] = (float)i1;
        out[NIDX + grow * 2 + 1] = (float)i2;
        out[NWTS + grow * 2 + 0] = p1 / dn;
        out[NWTS + grow * 2 + 1] = p2 / dn;
    }
    __syncthreads();

    // ---- probs write: 512 threads x 1 float4, coalesced ----
    {
        const int row = tid >> 4;
        const int e0  = (tid & 15) << 2;
        const float m = rowm[row], inv = rowinv[row];
        const long grow = rowbase + row;
        const float4 l4 = *reinterpret_cast<const float4*>(&lg[row * 68 + e0]);
        float4 p;
        p.x = __expf(l4.x - m) * inv;
        p.y = __expf(l4.y - m) * inv;
        p.z = __expf(l4.z - m) * inv;
        p.w = __expf(l4.w - m) * inv;
        *reinterpret_cast<float4*>(&out[grow * (long)NE + e0]) = p;
    }
}

extern "C" void kernel_launch(void* const* d_in, const int* in_sizes, int n_in,
                              void* d_out, int out_size, void* d_ws, size_t ws_size,
                              hipStream_t stream) {
    const float* x = (const float*)d_in[0];
    const float* W = (const float*)d_in[1];
    float* out = (float*)d_out;
    uint4* WF  = (uint4*)d_ws;   // 1.5 MB fragment-ordered W planes (32-wide tiles)

    w_prep<<<dim3(128), dim3(256), 0, stream>>>(W, WF);
    token_router<<<dim3(BT / BM), dim3(512), 0, stream>>>(x, WF, out);
}